// Round 2
// baseline (1261.244 us; speedup 1.0000x reference)
//
#include <hip/hip_runtime.h>

#define SEQ   256
#define DM    512
#define NH    8
#define HD    64
#define NB    8          // batch
#define MR    2048       // NB*SEQ rows
#define FLAT  131072     // SEQ*DM
#define FFN   1024

typedef __bf16 bf16;
typedef __bf16 bf16x8 __attribute__((ext_vector_type(8)));
typedef float  f32x4  __attribute__((ext_vector_type(4)));

static __device__ inline f32x4 mfma16(bf16x8 a, bf16x8 b, f32x4 c) {
  return __builtin_amdgcn_mfma_f32_16x16x32_bf16(a, b, c, 0, 0, 0);
}

static __device__ inline bf16x8 pack8(f32x4 a, f32x4 b) {
  bf16x8 o;
  o[0] = (bf16)a[0]; o[1] = (bf16)a[1]; o[2] = (bf16)a[2]; o[3] = (bf16)a[3];
  o[4] = (bf16)b[0]; o[5] = (bf16)b[1]; o[6] = (bf16)b[2]; o[7] = (bf16)b[3];
  return o;
}
static __device__ inline bf16x8 cvt8(const float* p) {
  return pack8(*(const f32x4*)p, *(const f32x4*)(p + 4));
}

// ---------------------------------------------------------------- layernorm
// fp32 in -> bf16 out. One wave per row.
__global__ __launch_bounds__(256) void ln_kernel(const float* __restrict__ x,
                                                 const float* __restrict__ lw,
                                                 const float* __restrict__ lb,
                                                 bf16* __restrict__ y) {
  int row  = blockIdx.x * 4 + (threadIdx.x >> 6);
  int lane = threadIdx.x & 63;
  f32x4 a = *(const f32x4*)(x + (size_t)row * DM + lane * 8);
  f32x4 b = *(const f32x4*)(x + (size_t)row * DM + lane * 8 + 4);
  float v[8];
#pragma unroll
  for (int j = 0; j < 4; ++j) { v[j] = a[j]; v[4 + j] = b[j]; }
  float s = 0.f;
#pragma unroll
  for (int j = 0; j < 8; ++j) s += v[j];
#pragma unroll
  for (int m = 32; m >= 1; m >>= 1) s += __shfl_xor(s, m, 64);
  float mu = s * (1.f / DM);
  float s2 = 0.f;
#pragma unroll
  for (int j = 0; j < 8; ++j) { float d = v[j] - mu; s2 += d * d; }
#pragma unroll
  for (int m = 32; m >= 1; m >>= 1) s2 += __shfl_xor(s2, m, 64);
  float rs = rsqrtf(s2 * (1.f / DM) + 1e-5f);
  f32x4 w0 = *(const f32x4*)(lw + lane * 8);
  f32x4 w1 = *(const f32x4*)(lw + lane * 8 + 4);
  f32x4 b0 = *(const f32x4*)(lb + lane * 8);
  f32x4 b1 = *(const f32x4*)(lb + lane * 8 + 4);
  bf16x8 o;
#pragma unroll
  for (int j = 0; j < 4; ++j) {
    o[j]     = (bf16)((v[j]     - mu) * rs * w0[j] + b0[j]);
    o[4 + j] = (bf16)((v[4 + j] - mu) * rs * w1[j] + b1[j]);
  }
  *(bf16x8*)(y + (size_t)row * DM + lane * 8) = o;
}

// ------------------------------------------- 512x512 weight transpose + cvt
// Wt[n][k] = (bf16)W[k][n] so GEMM B-fragments are k-contiguous 16B loads.
__global__ __launch_bounds__(256) void transpose_w(
    const float* __restrict__ Wq, const float* __restrict__ Wk,
    const float* __restrict__ Wv, const float* __restrict__ Wg,
    const float* __restrict__ Wo, bf16* __restrict__ Wt4,
    bf16* __restrict__ Wto) {
  int z = blockIdx.z;
  const float* src = (z == 0) ? Wq : (z == 1) ? Wk : (z == 2) ? Wv
                    : (z == 3) ? Wg : Wo;
  bf16* dst = (z < 4) ? (Wt4 + (size_t)z * DM * DM) : Wto;
  __shared__ bf16 tl[64][72];   // +8 pad breaks bank conflicts
  int t = threadIdx.x;
  int k0 = blockIdx.y * 64, n0 = blockIdx.x * 64;
  int r = t >> 3, c0 = (t & 7) * 8;
#pragma unroll
  for (int hh = 0; hh < 2; ++hh) {
    int rr = r + hh * 32;
    const float* sp = src + (size_t)(k0 + rr) * DM + n0 + c0;
    f32x4 v0 = *(const f32x4*)sp;
    f32x4 v1 = *(const f32x4*)(sp + 4);
#pragma unroll
    for (int j = 0; j < 4; ++j) {
      tl[rr][c0 + j]     = (bf16)v0[j];
      tl[rr][c0 + 4 + j] = (bf16)v1[j];
    }
  }
  __syncthreads();
#pragma unroll
  for (int hh = 0; hh < 2; ++hh) {
    int rr = r + hh * 32;   // output row (n)
    bf16x8 o;
#pragma unroll
    for (int j = 0; j < 8; ++j) o[j] = tl[c0 + j][rr];
    *(bf16x8*)(dst + (size_t)(n0 + rr) * DM + k0 + c0) = o;
  }
}

// ----------------------------------------------- QKVG GEMM  Xn @ {Wq..Wg}
// grid (16,16): x = m-block(128), y>>2 = weight sel, (y&3)*128 = n0.
// 4 waves of 64x64; no LDS, both operands bf16 from L2.
__global__ __launch_bounds__(256) void gemm_qkvg(
    const bf16* __restrict__ A, const bf16* __restrict__ Wt,
    bf16* __restrict__ out) {
  int m0  = blockIdx.x * 128;
  int sel = blockIdx.y >> 2;
  int n0  = (blockIdx.y & 3) * 128;
  const bf16* W  = Wt + (size_t)sel * DM * DM;
  bf16* dst      = out + (size_t)sel * MR * DM;
  int w = threadIdx.x >> 6, lane = threadIdx.x & 63;
  int mw = m0 + (w & 1) * 64, nw = n0 + (w >> 1) * 64;
  int lr = lane & 15, lk = (lane >> 4) * 8;
  f32x4 acc[4][4] = {};
  const bf16* Ap = A + (size_t)(mw + lr) * DM + lk;
  const bf16* Bp = W + (size_t)(nw + lr) * DM + lk;
  for (int ks = 0; ks < 16; ++ks) {
    bf16x8 af[4], bfr[4];
#pragma unroll
    for (int a = 0; a < 4; ++a)
      af[a] = *(const bf16x8*)(Ap + (size_t)a * 16 * DM + ks * 32);
#pragma unroll
    for (int bb = 0; bb < 4; ++bb)
      bfr[bb] = *(const bf16x8*)(Bp + (size_t)bb * 16 * DM + ks * 32);
#pragma unroll
    for (int a = 0; a < 4; ++a)
#pragma unroll
      for (int bb = 0; bb < 4; ++bb)
        acc[a][bb] = mfma16(af[a], bfr[bb], acc[a][bb]);
  }
#pragma unroll
  for (int a = 0; a < 4; ++a)
#pragma unroll
    for (int bb = 0; bb < 4; ++bb)
#pragma unroll
      for (int r = 0; r < 4; ++r) {
        int m = mw + a * 16 + (lane >> 4) * 4 + r;
        int n = nw + bb * 16 + lr;
        dst[(size_t)m * DM + n] = (bf16)acc[a][bb][r];
      }
}

// ------------------------------------------------- retention (+silu gate)
// grid (64 bh, 4 q-tiles of 64 rows). Linear decay attention, no softmax.
__global__ __launch_bounds__(256) void retention_kernel(
    const bf16* __restrict__ QKVG, bf16* __restrict__ T) {
  int bh = blockIdx.x, nt = blockIdx.y;
  int b = bh >> 3, h = bh & 7;
  const bf16* Q = QKVG;
  const bf16* K = QKVG + (size_t)MR * DM;
  const bf16* V = QKVG + (size_t)2 * MR * DM;
  const bf16* G = QKVG + (size_t)3 * MR * DM;
  int w = threadIdx.x >> 6, lane = threadIdx.x & 63;
  int lr = lane & 15, lq = lane >> 4, lk = lq * 8;
  __shared__ bf16 Vt[64 * 72];       // V^T tile, padded stride
  __shared__ bf16 Sl[4][16 * 72];    // per-wave decayed scores
  float l2g = log2f(1.0f - exp2f(-5.0f - (float)h));
  int qrow = b * SEQ + nt * 64 + w * 16 + lr;
  bf16x8 qf0 = *(const bf16x8*)(Q + (size_t)qrow * DM + h * HD + lk);
  bf16x8 qf1 = *(const bf16x8*)(Q + (size_t)qrow * DM + h * HD + lk + 32);
  f32x4 od[4] = {};
  bf16* sw = &Sl[w][0];
  for (int mt = 0; mt <= nt; ++mt) {
    { // stage V^T cooperatively
      int tm = threadIdx.x >> 2;
      int td = (threadIdx.x & 3) * 16;
      const bf16* vp = V + (size_t)(b * SEQ + mt * 64 + tm) * DM + h * HD + td;
      bf16x8 v0 = *(const bf16x8*)vp;
      bf16x8 v1 = *(const bf16x8*)(vp + 8);
#pragma unroll
      for (int j = 0; j < 8; ++j) {
        Vt[(td + j) * 72 + tm]     = v0[j];
        Vt[(td + 8 + j) * 72 + tm] = v1[j];
      }
    }
    __syncthreads();
    // S = Q K^T  (C: row = q-row, col = k-row)
    f32x4 sc[4] = {};
#pragma unroll
    for (int t = 0; t < 4; ++t) {
      int krow = b * SEQ + mt * 64 + t * 16 + lr;
      bf16x8 k0 = *(const bf16x8*)(K + (size_t)krow * DM + h * HD + lk);
      bf16x8 k1 = *(const bf16x8*)(K + (size_t)krow * DM + h * HD + lk + 32);
      sc[t] = mfma16(qf0, k0, sc[t]);
      sc[t] = mfma16(qf1, k1, sc[t]);
    }
    // decay + 1/8 scale, write bf16 S to LDS in A-layout order
#pragma unroll
    for (int t = 0; t < 4; ++t)
#pragma unroll
      for (int r = 0; r < 4; ++r) {
        int n = nt * 64 + w * 16 + lq * 4 + r;
        int m = mt * 64 + t * 16 + lr;
        int d = n - m;
        float val = (d >= 0) ? sc[t][r] * 0.125f * exp2f((float)d * l2g) : 0.f;
        sw[(lq * 4 + r) * 72 + t * 16 + lr] = (bf16)val;
      }
    __syncthreads();
    // O += S @ V
#pragma unroll
    for (int ks = 0; ks < 2; ++ks) {
      bf16x8 sf = *(const bf16x8*)(sw + lr * 72 + ks * 32 + lk);
#pragma unroll
      for (int dt = 0; dt < 4; ++dt) {
        bf16x8 vf = *(const bf16x8*)(&Vt[(dt * 16 + lr) * 72 + ks * 32 + lk]);
        od[dt] = mfma16(sf, vf, od[dt]);
      }
    }
    __syncthreads();   // before Vt overwrite
  }
  // epilogue: T = silu(G) * O
#pragma unroll
  for (int dt = 0; dt < 4; ++dt)
#pragma unroll
    for (int r = 0; r < 4; ++r) {
      int n = nt * 64 + w * 16 + lq * 4 + r;
      int d = dt * 16 + lr;
      size_t idx = (size_t)(b * SEQ + n) * DM + h * HD + d;
      float g  = (float)G[idx];
      float sg = g / (1.0f + expf(-g));
      T[idx] = (bf16)(od[dt][r] * sg);
    }
}

// ------------------------------------------ W_O GEMM + residual, fp32 out
// grid (16,8): 128-row x 64-col tiles; 4 waves of 32x64.
__global__ __launch_bounds__(256) void gemm_wo(
    const bf16* __restrict__ A, const bf16* __restrict__ Wt,
    const float* __restrict__ Xres, float* __restrict__ Y) {
  int m0 = blockIdx.x * 128, n0 = blockIdx.y * 64;
  int w = threadIdx.x >> 6, lane = threadIdx.x & 63;
  int mw = m0 + w * 32;
  int lr = lane & 15, lk = (lane >> 4) * 8;
  f32x4 acc[2][4] = {};
  const bf16* Ap = A + (size_t)(mw + lr) * DM + lk;
  const bf16* Bp = Wt + (size_t)(n0 + lr) * DM + lk;
  for (int ks = 0; ks < 16; ++ks) {
    bf16x8 af[2], bfr[4];
#pragma unroll
    for (int a = 0; a < 2; ++a)
      af[a] = *(const bf16x8*)(Ap + (size_t)a * 16 * DM + ks * 32);
#pragma unroll
    for (int bb = 0; bb < 4; ++bb)
      bfr[bb] = *(const bf16x8*)(Bp + (size_t)bb * 16 * DM + ks * 32);
#pragma unroll
    for (int a = 0; a < 2; ++a)
#pragma unroll
      for (int bb = 0; bb < 4; ++bb)
        acc[a][bb] = mfma16(af[a], bfr[bb], acc[a][bb]);
  }
#pragma unroll
  for (int a = 0; a < 2; ++a)
#pragma unroll
    for (int bb = 0; bb < 4; ++bb)
#pragma unroll
      for (int r = 0; r < 4; ++r) {
        int m = mw + a * 16 + (lane >> 4) * 4 + r;
        int n = n0 + bb * 16 + lr;
        size_t idx = (size_t)m * DM + n;
        Y[idx] = acc[a][bb][r] + Xres[idx];
      }
}

// ------------------------------------------------ FFN1: h += Zn @ W1^T chunk
// split-K: grid 512, each block a 256-wide i-chunk over all 1024 f.
// W1 streamed fp32, packed to bf16 in regs.
__global__ __launch_bounds__(256) void ffn1_kernel(
    const bf16* __restrict__ Zn, const float* __restrict__ W1,
    float* __restrict__ hpre) {
  int k0 = blockIdx.x * 256;
  int t = threadIdx.x;
  int w = t >> 6, lane = t & 63;
  int lr = lane & 15, lk = (lane >> 4) * 8;
  f32x4 acc[16] = {};
  const bf16*  ap = Zn + (size_t)lr * FLAT + k0 + lk;   // rows 8..15 masked
  const float* wp = W1 + (size_t)(w * 256 + lr) * FLAT + k0 + lk;
  bool am = lr < 8;
  for (int ks = 0; ks < 8; ++ks) {
    bf16x8 af = {};
    if (am) af = *(const bf16x8*)(ap + ks * 32);
#pragma unroll
    for (int tt = 0; tt < 16; ++tt) {
      bf16x8 bfr = cvt8(wp + (size_t)tt * 16 * FLAT + ks * 32);
      acc[tt] = mfma16(af, bfr, acc[tt]);
    }
  }
  if (lane < 32) {
#pragma unroll
    for (int tt = 0; tt < 16; ++tt)
#pragma unroll
      for (int r = 0; r < 4; ++r) {
        int bb = (lane >> 4) * 4 + r;   // batch 0..7
        atomicAdd(&hpre[bb * FFN + w * 256 + tt * 16 + lr], acc[tt][r]);
      }
  }
}

// --------------------------- FFN2: out = gelu(h) @ W2^T + Ysupl, fp32 out
// grid 512; block stages gelu(h) bf16 in LDS; each wave streams 4 i-rows'
// fp32 W2 with a 2-slot raw-register prefetch, packs to bf16 at use.
__global__ __launch_bounds__(256) void ffn2_kernel(
    const float* __restrict__ hpre, const float* __restrict__ W2,
    const float* __restrict__ Ys, float* __restrict__ out) {
  __shared__ bf16 hA[16 * 1032];
  int t = threadIdx.x;
  {
    int row = t >> 4;
    int c0  = (t & 15) * 64;
    if (row < 8) {
#pragma unroll 4
      for (int jj = 0; jj < 16; ++jj) {
        f32x4 v = *(const f32x4*)(hpre + row * FFN + c0 + jj * 4);
#pragma unroll
        for (int r = 0; r < 4; ++r) {
          float xv = v[r];
          hA[row * 1032 + c0 + jj * 4 + r] =
              (bf16)(0.5f * xv * (1.f + erff(xv * 0.70710678f)));
        }
      }
    } else {
      for (int j = 0; j < 64; ++j) hA[row * 1032 + c0 + j] = (bf16)0.f;
    }
  }
  __syncthreads();
  int w = t >> 6, lane = t & 63;
  int lr = lane & 15, lk = (lane >> 4) * 8;
  int ibase = blockIdx.x * 256 + w * 64;
  const float* bp[4];
#pragma unroll
  for (int tt = 0; tt < 4; ++tt)
    bp[tt] = W2 + (size_t)(ibase + tt * 16 + lr) * FFN + lk;
  const bf16* ap = hA + lr * 1032 + lk;
  f32x4 acc[4] = {};
  bf16x8 ac[2];
  f32x4 braw[2][4][2];
  ac[0] = *(const bf16x8*)ap;
  ac[1] = *(const bf16x8*)(ap + 32);
#pragma unroll
  for (int s = 0; s < 2; ++s)
#pragma unroll
    for (int tt = 0; tt < 4; ++tt) {
      braw[s][tt][0] = *(const f32x4*)(bp[tt] + s * 32);
      braw[s][tt][1] = *(const f32x4*)(bp[tt] + s * 32 + 4);
    }
  for (int ks = 0; ks < 32; ++ks) {
    int cur = ks & 1;
    bf16x8 an = {};
    f32x4 nraw[4][2];
    if (ks < 30) {
      an = *(const bf16x8*)(ap + (ks + 2) * 32);
#pragma unroll
      for (int tt = 0; tt < 4; ++tt) {
        nraw[tt][0] = *(const f32x4*)(bp[tt] + (ks + 2) * 32);
        nraw[tt][1] = *(const f32x4*)(bp[tt] + (ks + 2) * 32 + 4);
      }
    }
#pragma unroll
    for (int tt = 0; tt < 4; ++tt) {
      bf16x8 bfrag = pack8(braw[cur][tt][0], braw[cur][tt][1]);
      acc[tt] = mfma16(ac[cur], bfrag, acc[tt]);
    }
    ac[cur] = an;
#pragma unroll
    for (int tt = 0; tt < 4; ++tt) {
      braw[cur][tt][0] = nraw[tt][0];
      braw[cur][tt][1] = nraw[tt][1];
    }
  }
  if (lane < 32) {
#pragma unroll
    for (int tt = 0; tt < 4; ++tt)
#pragma unroll
      for (int r = 0; r < 4; ++r) {
        int bb = (lane >> 4) * 4 + r;   // batch
        size_t idx = (size_t)bb * FLAT + ibase + tt * 16 + lr;
        out[idx] = acc[tt][r] + Ys[idx];
      }
  }
}

// --------------------------------------------------------------- launcher
extern "C" void kernel_launch(void* const* d_in, const int* in_sizes, int n_in,
                              void* d_out, int out_size, void* d_ws, size_t ws_size,
                              hipStream_t stream) {
  const float* X   = (const float*)d_in[0];
  const float* Wq  = (const float*)d_in[1];
  const float* Wk  = (const float*)d_in[2];
  const float* Wv  = (const float*)d_in[3];
  const float* Wg  = (const float*)d_in[4];
  const float* Wo  = (const float*)d_in[5];
  const float* lnw = (const float*)d_in[6];
  const float* lnb = (const float*)d_in[7];
  const float* W1  = (const float*)d_in[8];
  const float* W2  = (const float*)d_in[9];
  float* out = (float*)d_out;

  char* ws = (char*)d_ws;
  bf16*  Xn   = (bf16*)(ws);                    // 2 MB  LN1(X) bf16
  bf16*  QKVG = (bf16*)(ws + (2ull  << 20));    // 8 MB  Q|K|V|G bf16
  bf16*  Tbuf = (bf16*)(ws + (10ull << 20));    // 2 MB  silu(G)*ret bf16
  bf16*  Wt4  = (bf16*)(ws + (12ull << 20));    // 2 MB  Wq..Wg transposed bf16
  bf16*  Wto  = (bf16*)(ws + (14ull << 20));    // 0.5MB Wo transposed bf16
  float* Ys   = (float*)(ws + (15ull << 20));   // 4 MB  Ysupl fp32
  bf16*  Zn   = (bf16*)(ws + (19ull << 20));    // 2 MB  LN2(Ysupl) bf16
  float* hpre = (float*)(ws + (21ull << 20));   // 32 KB FFN hidden pre-act

  transpose_w<<<dim3(8, 8, 5), 256, 0, stream>>>(Wq, Wk, Wv, Wg, Wo, Wt4, Wto);
  ln_kernel<<<512, 256, 0, stream>>>(X, lnw, lnb, Xn);
  gemm_qkvg<<<dim3(16, 16), 256, 0, stream>>>(Xn, Wt4, QKVG);
  retention_kernel<<<dim3(64, 4), 256, 0, stream>>>(QKVG, Tbuf);
  gemm_wo<<<dim3(16, 8), 256, 0, stream>>>(Tbuf, Wto, X, Ys);
  ln_kernel<<<512, 256, 0, stream>>>(Ys, lnw, lnb, Zn);
  hipMemsetAsync(hpre, 0, NB * FFN * sizeof(float), stream);
  ffn1_kernel<<<512, 256, 0, stream>>>(Zn, W1, hpre);
  ffn2_kernel<<<512, 256, 0, stream>>>(hpre, W2, Ys, out);
}